// Round 2
// baseline (899.275 us; speedup 1.0000x reference)
//
#include <hip/hip_runtime.h>
#include <stdint.h>

typedef unsigned short u16;
typedef __attribute__((ext_vector_type(8))) _Float16 half8;
typedef __attribute__((ext_vector_type(4))) _Float16 half4;
typedef __attribute__((ext_vector_type(4))) float floatx4;

// ---------- helpers ----------
__device__ inline float bflo(unsigned u){ return __uint_as_float(u << 16); }
__device__ inline float bfhi(unsigned u){ return __uint_as_float(u & 0xffff0000u); }
__device__ inline float bf1(u16 v){ return __uint_as_float(((unsigned)v) << 16); }
__device__ inline u16 f2bf(float f){
  unsigned u = __float_as_uint(f);
  u += 0x7fffu + ((u >> 16) & 1u);           // RNE
  return (u16)(u >> 16);
}
__device__ inline float dot8(uint4 w, float4 a, float4 b, float acc){
  acc = fmaf(bflo(w.x), a.x, acc); acc = fmaf(bfhi(w.x), a.y, acc);
  acc = fmaf(bflo(w.y), a.z, acc); acc = fmaf(bfhi(w.y), a.w, acc);
  acc = fmaf(bflo(w.z), b.x, acc); acc = fmaf(bfhi(w.z), b.y, acc);
  acc = fmaf(bflo(w.w), b.z, acc); acc = fmaf(bfhi(w.w), b.w, acc);
  return acc;
}

// canonical weight buffer offsets (u16 elements), d_in order (skipping inputs)
#define CW_SLOTS 0
#define CW_GIN   4096
#define CW_BIN   4352
#define CW_GS    4608
#define CW_BS    4864
#define CW_GM    5120
#define CW_BM    5376
#define CW_WQ    5632
#define CW_WK    71168
#define CW_WV    136704
#define CW_WIH   202240
#define CW_WHH   398848
#define CW_BIH   595456
#define CW_BHH   596224
#define CW_W1    596992
#define CW_B1    728064
#define CW_W2    728576
#define CW_B2    859648
#define CW_TOTAL 859904

// ---------- dtype probe ----------
__global__ void k_flag(const u16* __restrict__ probe, int* __restrict__ flag){
  int t = threadIdx.x;
  int bad = 0;
  #pragma unroll
  for (int i = 0; i < 4; i++){
    float x = bf1(probe[t + i * 256]);
    if (!(fabsf(x) < 1e6f)) bad = 1;
  }
  __shared__ int s;
  if (t == 0) s = 0;
  __syncthreads();
  if (bad) atomicOr(&s, 1);
  __syncthreads();
  if (t == 0) *flag = s;
}

// ---------- canonicalize all weight/bias arrays to bf16 in ws ----------
struct CanonArgs { const void* p[18]; };

__global__ void k_canon(CanonArgs a, const int* __restrict__ flag, u16* __restrict__ cw){
  const int off[19] = {CW_SLOTS, CW_GIN, CW_BIN, CW_GS, CW_BS, CW_GM, CW_BM, CW_WQ,
                       CW_WK, CW_WV, CW_WIH, CW_WHH, CW_BIH, CW_BHH, CW_W1, CW_B1,
                       CW_W2, CW_B2, CW_TOTAL};
  int i = blockIdx.x * 256 + threadIdx.x;
  if (i >= CW_TOTAL) return;
  int f32m = *flag;
  int j = 0;
  while (i >= off[j + 1]) j++;
  int local = i - off[j];
  float v = f32m ? ((const float*)a.p[j])[local] : bf1(((const u16*)a.p[j])[local]);
  cw[i] = f2bf(v);
}

// ---------- init: wkvh[c][d] = Wkv[c][d]*gin[d] (fp16); broadcast slots -> f32 ----------
__global__ void k_init(const u16* __restrict__ cw, float* __restrict__ slots,
                       _Float16* __restrict__ wkvh)
{
  int idx = blockIdx.x * 256 + threadIdx.x;      // 0..262143
  if (idx < 131072){
    float g = bf1(cw[CW_GIN + (idx & 255)]);
    wkvh[idx] = (_Float16)(bf1(cw[CW_WK + idx]) * g);   // Wk|Wv contiguous
  } else {
    int i = idx - 131072;
    int d = i & 255;
    int q = (i >> 8) & 15;
    slots[i] = bf1(cw[CW_SLOTS + q * 256 + d]);
  }
}

// beta[c] = sum_d bin[d]*Wkv[c][d]; colsum[c] = sum_d gin[d]*Wkv[c][d]   (512 cols)
__global__ void k_beta(const u16* __restrict__ cw, float* __restrict__ beta,
                       float* __restrict__ colsum){
  int c = blockIdx.x * 256 + threadIdx.x;
  if (c >= 512) return;
  float a = 0.f, s = 0.f;
  for (int d = 0; d < 256; d++){
    float w = bf1(cw[CW_WK + c * 256 + d]);
    a = fmaf(bf1(cw[CW_BIN + d]), w, a);
    s = fmaf(bf1(cw[CW_GIN + d]), w, s);
  }
  beta[c] = a;
  colsum[c] = s;
}

__global__ void k_zero(float* __restrict__ p, int n){
  int i = blockIdx.x * 256 + threadIdx.x;
  if (i < n) p[i] = 0.f;
}

// ---------- K1: fused LN-stats + GEMM; 128 rows/block ----------
// LN is folded into the epilogue: out = rstd*(dot(W*g, x_raw) - mu*colsum) + beta.
// nb==1 (vT) output is staged in LDS and drained in 128B-contiguous chunks.
__global__ __launch_bounds__(256) void k1_gemm(
    const void* __restrict__ inp, const int* __restrict__ flag,
    const float* __restrict__ beta, const float* __restrict__ colsum,
    const _Float16* __restrict__ wkvh, _Float16* __restrict__ kh, _Float16* __restrict__ vT)
{
  int f32m = *flag;
  int tid = threadIdx.x;
  int wv = tid >> 6, lane = tid & 63;
  int m16 = lane & 15, q4 = lane >> 4;
  int nb = blockIdx.y;
  long rowb0 = (long)blockIdx.x * 128;
  int colW = nb * 256 + wv * 64;                  // wave's base col

  __shared__ _Float16 vtile[256][72];             // 36 KB; [cv][key(64)+pad]

  half8 bfr[4][8];
  #pragma unroll
  for (int nt = 0; nt < 4; nt++)
    #pragma unroll
    for (int s = 0; s < 8; s++)
      bfr[nt][s] = *(const half8*)(wkvh + (colW + nt * 16 + m16) * 256 + s * 32 + q4 * 8);

  float bet[4], cs[4];
  #pragma unroll
  for (int nt = 0; nt < 4; nt++){
    bet[nt] = beta[colW + nt * 16 + m16];
    cs[nt]  = colsum[colW + nt * 16 + m16];
  }

  for (int rt = 0; rt < 8; rt++){
    long rowb = rowb0 + rt * 16;
    long myRow = rowb + m16;

    // load raw row quarter, accumulate f32 stats, keep raw f16 fragments
    float sum = 0.f, sq = 0.f;
    half8 af[8];
    if (f32m){
      const float* rp = (const float*)inp + myRow * 256 + q4 * 8;
      #pragma unroll
      for (int s = 0; s < 8; s++){
        float4 x0 = *(const float4*)(rp + s * 32);
        float4 x1 = *(const float4*)(rp + s * 32 + 4);
        sum += x0.x + x0.y + x0.z + x0.w + x1.x + x1.y + x1.z + x1.w;
        sq = fmaf(x0.x, x0.x, sq); sq = fmaf(x0.y, x0.y, sq);
        sq = fmaf(x0.z, x0.z, sq); sq = fmaf(x0.w, x0.w, sq);
        sq = fmaf(x1.x, x1.x, sq); sq = fmaf(x1.y, x1.y, sq);
        sq = fmaf(x1.z, x1.z, sq); sq = fmaf(x1.w, x1.w, sq);
        af[s][0] = (_Float16)x0.x; af[s][1] = (_Float16)x0.y;
        af[s][2] = (_Float16)x0.z; af[s][3] = (_Float16)x0.w;
        af[s][4] = (_Float16)x1.x; af[s][5] = (_Float16)x1.y;
        af[s][6] = (_Float16)x1.z; af[s][7] = (_Float16)x1.w;
      }
    } else {
      const u16* rp = (const u16*)inp + myRow * 256 + q4 * 8;
      #pragma unroll
      for (int s = 0; s < 8; s++){
        uint4 xu = *(const uint4*)(rp + s * 32);
        unsigned xw[4] = {xu.x, xu.y, xu.z, xu.w};
        #pragma unroll
        for (int p = 0; p < 4; p++){
          float a = bflo(xw[p]), b = bfhi(xw[p]);
          sum += a + b; sq = fmaf(a, a, sq); sq = fmaf(b, b, sq);
          af[s][2*p]   = (_Float16)a;
          af[s][2*p+1] = (_Float16)b;
        }
      }
    }
    // reduce across the 4 q4-lanes sharing this row (lane bits 4,5)
    sum += __shfl_xor(sum, 16); sq += __shfl_xor(sq, 16);
    sum += __shfl_xor(sum, 32); sq += __shfl_xor(sq, 32);
    float mu = sum * (1.f/256.f);
    float rstd = rsqrtf(fmaf(-mu, mu, sq * (1.f/256.f)) + 1e-5f);

    floatx4 acc[4];
    #pragma unroll
    for (int nt = 0; nt < 4; nt++) acc[nt] = (floatx4)0.f;
    #pragma unroll
    for (int s = 0; s < 8; s++)
      #pragma unroll
      for (int nt = 0; nt < 4; nt++)
        acc[nt] = __builtin_amdgcn_mfma_f32_16x16x32_f16(af[s], bfr[nt][s], acc[nt], 0, 0, 0);

    // gather stats of the 4 output rows this lane holds (rows q4*4+r live on lanes q4*4+r)
    float mur[4], rsr[4];
    #pragma unroll
    for (int r = 0; r < 4; r++){
      mur[r] = __shfl(mu,   q4 * 4 + r);
      rsr[r] = __shfl(rstd, q4 * 4 + r);
    }
    // epilogue: out = rstd*(acc - mu*colsum) + beta
    #pragma unroll
    for (int nt = 0; nt < 4; nt++)
      #pragma unroll
      for (int r = 0; r < 4; r++)
        acc[nt][r] = fmaf(rsr[r], fmaf(-mur[r], cs[nt], acc[nt][r]), bet[nt]);

    if (nb == 0){
      long crow = rowb + q4 * 4;
      #pragma unroll
      for (int nt = 0; nt < 4; nt++)
        #pragma unroll
        for (int r = 0; r < 4; r++)
          kh[(crow + r) * 256 + colW + nt * 16 + m16] = (_Float16)acc[nt][r];
    } else {
      int klocal = (rt & 3) * 16 + q4 * 4;
      #pragma unroll
      for (int nt = 0; nt < 4; nt++){
        int cv = (colW - 256) + nt * 16 + m16;
        half4 pk;
        pk[0] = (_Float16)acc[nt][0]; pk[1] = (_Float16)acc[nt][1];
        pk[2] = (_Float16)acc[nt][2]; pk[3] = (_Float16)acc[nt][3];
        *(half4*)&vtile[cv][klocal] = pk;
      }
      if ((rt & 3) == 3){
        __syncthreads();
        int b = (int)(rowb0 >> 12);
        int keyb = ((int)rowb0 & 4095) + (rt >> 2) * 64;
        int cvo = wv * 8 + (lane >> 3);
        int k8  = (lane & 7) * 8;
        #pragma unroll
        for (int pass = 0; pass < 8; pass++){
          int cv = pass * 32 + cvo;
          half8 vvv = *(const half8*)&vtile[cv][k8];
          *(half8*)(vT + ((long)b * 256 + cv) * 4096 + keyb + k8) = vvv;
        }
        __syncthreads();
      }
    }
  }
}

// ---------- K2: slot LN + q projection ----------
__global__ __launch_bounds__(256) void k2_q(
    const float* __restrict__ slots, const u16* __restrict__ cw, _Float16* __restrict__ qh)
{
  const u16* gq = cw + CW_GS;
  const u16* bq = cw + CW_BS;
  const u16* Wq = cw + CW_WQ;
  int row = blockIdx.x, tid = threadIdx.x;
  int wv = tid >> 6, lane = tid & 63;
  float x = slots[row * 256 + tid];
  float s = x, s2 = x * x;
  #pragma unroll
  for (int m = 1; m < 64; m <<= 1){ s += __shfl_xor(s, m); s2 += __shfl_xor(s2, m); }
  __shared__ float red[8];
  if (lane == 0){ red[wv] = s; red[4 + wv] = s2; }
  __syncthreads();
  float tot  = red[0] + red[1] + red[2] + red[3];
  float tot2 = red[4] + red[5] + red[6] + red[7];
  float mu = tot * (1.f/256.f);
  float rstd = rsqrtf(tot2 * (1.f/256.f) - mu * mu + 1e-5f);
  __shared__ float sln[256];
  sln[tid] = (x - mu) * rstd * bf1(gq[tid]) + bf1(bq[tid]);
  __syncthreads();
  const u16* wr = Wq + tid * 256;
  float a = 0.f;
  for (int k = 0; k < 256; k += 8){
    uint4 wu = *(const uint4*)(wr + k);
    float4 l0 = *(const float4*)(sln + k);
    float4 l1 = *(const float4*)(sln + k + 4);
    a = dot8(wu, l0, l1, a);
  }
  qh[row * 256 + tid] = (_Float16)(a * 0.17677669529663687f);
}

// ---------- K3: logits(MFMA) + joint softmax + MFMA numer (f32 atomics) ----------
// grid (16 chunks of 256 keys, 32 batches); wave w owns heads 2w,2w+1.
// On lastIter also writes attn_vis directly (phase B already has sl, St).
__global__ __launch_bounds__(256) void k3_attn(
    const _Float16* __restrict__ kh, const _Float16* __restrict__ vT,
    const _Float16* __restrict__ qh,
    float* __restrict__ denom, float* __restrict__ numer,
    void* __restrict__ out_base, const int* __restrict__ flag, int lastIter)
{
  int f32m = *flag;
  int tid = threadIdx.x;
  int wv = tid >> 6, lane = tid & 63;
  int m16 = lane & 15, q4 = lane >> 4;
  int b = blockIdx.y, chunk = blockIdx.x;
  __shared__ float lds_l[32 * 129];               // [key 0..31][h*16+q]

  half8 qf[2];
  #pragma unroll
  for (int hh = 0; hh < 2; hh++){
    int h = wv * 2 + hh;
    qf[hh] = *(const half8*)(qh + (b * 16 + m16) * 256 + h * 32 + q4 * 8);
  }
  float pd[2] = {0.f, 0.f};
  floatx4 un[2][2];
  #pragma unroll
  for (int hh = 0; hh < 2; hh++)
    #pragma unroll
    for (int dt = 0; dt < 2; dt++) un[hh][dt] = (floatx4)0.f;

  floatx4 z4 = (floatx4)0.f;
  for (int g4 = 0; g4 < 8; g4++){
    int key0 = chunk * 256 + g4 * 32;
    // phase A: logits for 32 keys x 2 heads per wave
    #pragma unroll
    for (int sub = 0; sub < 2; sub++){
      long rowb = (long)b * 4096 + key0 + sub * 16;
      #pragma unroll
      for (int hh = 0; hh < 2; hh++){
        int h = wv * 2 + hh;
        half8 af = *(const half8*)(kh + (rowb + m16) * 256 + h * 32 + q4 * 8);
        floatx4 d = __builtin_amdgcn_mfma_f32_16x16x32_f16(af, qf[hh], z4, 0, 0, 0);
        #pragma unroll
        for (int r = 0; r < 4; r++)
          lds_l[(sub * 16 + q4 * 4 + r) * 129 + h * 16 + m16] = d[r];
      }
    }
    __syncthreads();
    // phase B: per-key joint softmax over 128 (h,q); each thread does 2 keys
    {
      int qq = tid & 15;
      #pragma unroll
      for (int half_ = 0; half_ < 2; half_++){
        int kk = (tid >> 4) + half_ * 16;
        float l[8];
        #pragma unroll
        for (int h8 = 0; h8 < 8; h8++) l[h8] = lds_l[kk * 129 + h8 * 16 + qq];
        float M = l[0];
        #pragma unroll
        for (int h8 = 1; h8 < 8; h8++) M = fmaxf(M, l[h8]);
        #pragma unroll
        for (int msk = 1; msk < 16; msk <<= 1) M = fmaxf(M, __shfl_xor(M, msk));
        float p[8], sl = 0.f;
        #pragma unroll
        for (int h8 = 0; h8 < 8; h8++){ p[h8] = __expf(l[h8] - M); sl += p[h8]; }
        float St = sl;
        #pragma unroll
        for (int msk = 1; msk < 16; msk <<= 1) St += __shfl_xor(St, msk);
        float rS = 1.f / St;
        if (lastIter){
          float av = sl * rS;                     // attn_vis = sum over heads
          long idx = 131072 + ((long)b * 4096 + key0 + kk) * 16 + qq;
          if (f32m) ((float*)out_base)[idx] = av;
          else      ((u16*)out_base)[idx]   = f2bf(av);
        }
        #pragma unroll
        for (int h8 = 0; h8 < 8; h8++) lds_l[kk * 129 + h8 * 16 + qq] = p[h8] * rS;
      }
    }
    __syncthreads();
    // phase C: U[d][q] += vT[d][key] * P[key][q] via MFMA over 32 keys
    #pragma unroll
    for (int hh = 0; hh < 2; hh++){
      int h = wv * 2 + hh;
      float pv[8];
      #pragma unroll
      for (int j = 0; j < 8; j++) pv[j] = lds_l[(q4 * 8 + j) * 129 + h * 16 + m16];
      float ps = 0.f;
      #pragma unroll
      for (int j = 0; j < 8; j++) ps += pv[j];
      pd[hh] += ps;
      half8 bfr;
      #pragma unroll
      for (int j = 0; j < 8; j++) bfr[j] = (_Float16)pv[j];
      #pragma unroll
      for (int dt = 0; dt < 2; dt++){
        half8 afr = *(const half8*)(vT + ((long)b * 256 + h * 32 + dt * 16 + m16) * 4096 + key0 + q4 * 8);
        un[hh][dt] = __builtin_amdgcn_mfma_f32_16x16x32_f16(afr, bfr, un[hh][dt], 0, 0, 0);
      }
    }
    __syncthreads();
  }
  // f32 atomics straight into numer/denom (no f16 partials, no reduce pass)
  #pragma unroll
  for (int hh = 0; hh < 2; hh++){
    int h = wv * 2 + hh;
    float t = pd[hh];
    t += __shfl_xor(t, 16); t += __shfl_xor(t, 32);
    if (q4 == 0) atomicAdd(&denom[(b * 8 + h) * 16 + m16], t);
    #pragma unroll
    for (int dt = 0; dt < 2; dt++)
      #pragma unroll
      for (int r = 0; r < 4; r++)
        atomicAdd(&numer[((b * 8 + h) * 16 + m16) * 32 + dt * 16 + q4 * 4 + r], un[hh][dt][r]);
  }
}

// ---------- K4a: GRU cell -> mid (f32) ----------
__global__ __launch_bounds__(256) void k4a_gru(
    const float* __restrict__ slots, const float* __restrict__ numer, const float* __restrict__ denom,
    const u16* __restrict__ cw, float* __restrict__ mid)
{
  const u16* wih = cw + CW_WIH;
  const u16* whh = cw + CW_WHH;
  const u16* bih = cw + CW_BIH;
  const u16* bhh = cw + CW_BHH;
  int jc = blockIdx.x, rg = blockIdx.y;
  int tid = threadIdx.x;
  __shared__ float u_s[8][256];
  __shared__ float h_s[8][256];
  {
    int hh = tid >> 5, dh = tid & 31;
    for (int i = 0; i < 8; i++){
      int row = rg * 8 + i;
      int b = row >> 4, slot = row & 15;
      float den = denom[(b * 8 + hh) * 16 + slot] + 1e-8f;
      u_s[i][tid] = numer[((b * 8 + hh) * 16 + slot) * 32 + dh] / den;
      h_s[i][tid] = slots[row * 256 + tid];
    }
  }
  __syncthreads();
  int rl = tid >> 5, jl = tid & 31;
  int j = jc * 32 + jl;
  int row = rg * 8 + rl;
  const u16* wir = wih + j * 256;
  const u16* wiz = wih + (256 + j) * 256;
  const u16* win = wih + (512 + j) * 256;
  const u16* whr = whh + j * 256;
  const u16* whz = whh + (256 + j) * 256;
  const u16* whn = whh + (512 + j) * 256;
  float air = 0, aiz = 0, ain = 0, ahr = 0, ahz = 0, ahn = 0;
  for (int k = 0; k < 256; k += 8){
    float4 u0 = *(const float4*)(&u_s[rl][k]);
    float4 u1 = *(const float4*)(&u_s[rl][k + 4]);
    float4 h0 = *(const float4*)(&h_s[rl][k]);
    float4 h1 = *(const float4*)(&h_s[rl][k + 4]);
    air = dot8(*(const uint4*)(wir + k), u0, u1, air);
    aiz = dot8(*(const uint4*)(wiz + k), u0, u1, aiz);
    ain = dot8(*(const uint4*)(win + k), u0, u1, ain);
    ahr = dot8(*(const uint4*)(whr + k), h0, h1, ahr);
    ahz = dot8(*(const uint4*)(whz + k), h0, h1, ahz);
    ahn = dot8(*(const uint4*)(whn + k), h0, h1, ahn);
  }
  float gr = air + bf1(bih[j])       + ahr + bf1(bhh[j]);
  float gz = aiz + bf1(bih[256 + j]) + ahz + bf1(bhh[256 + j]);
  float r = 1.f / (1.f + __expf(-gr));
  float z = 1.f / (1.f + __expf(-gz));
  float nn = tanhf(ain + bf1(bih[512 + j]) + r * (ahn + bf1(bhh[512 + j])));
  float h = h_s[rl][j];
  mid[row * 256 + j] = (1.f - z) * nn + z * h;
}

// ---------- K4b: LN + MLP + residual ----------
__global__ __launch_bounds__(256) void k4b_mlp(
    const float* __restrict__ mid, const u16* __restrict__ cw,
    float* __restrict__ slots, void* __restrict__ out_base,
    const int* __restrict__ flag, int lastIter)
{
  int f32m = *flag;
  const u16* gm = cw + CW_GM;
  const u16* bm = cw + CW_BM;
  const u16* w1 = cw + CW_W1;
  const u16* b1 = cw + CW_B1;
  const u16* w2 = cw + CW_W2;
  const u16* b2 = cw + CW_B2;
  int row = blockIdx.x, tid = threadIdx.x;
  int wv = tid >> 6, lane = tid & 63;
  float x = mid[row * 256 + tid];
  float s = x, s2 = x * x;
  #pragma unroll
  for (int m = 1; m < 64; m <<= 1){ s += __shfl_xor(s, m); s2 += __shfl_xor(s2, m); }
  __shared__ float red[8];
  if (lane == 0){ red[wv] = s; red[4 + wv] = s2; }
  __syncthreads();
  float tot  = red[0] + red[1] + red[2] + red[3];
  float tot2 = red[4] + red[5] + red[6] + red[7];
  float mu = tot * (1.f/256.f);
  float rstd = rsqrtf(tot2 * (1.f/256.f) - mu * mu + 1e-5f);
  __shared__ float ls[256];
  __shared__ float h1[512];
  ls[tid] = (x - mu) * rstd * bf1(gm[tid]) + bf1(bm[tid]);
  __syncthreads();
  const u16* w1a = w1 + tid * 256;
  const u16* w1b = w1 + (tid + 256) * 256;
  float a0 = 0.f, a1 = 0.f;
  for (int k = 0; k < 256; k += 8){
    float4 l0 = *(const float4*)(ls + k);
    float4 l1 = *(const float4*)(ls + k + 4);
    a0 = dot8(*(const uint4*)(w1a + k), l0, l1, a0);
    a1 = dot8(*(const uint4*)(w1b + k), l0, l1, a1);
  }
  h1[tid]       = fmaxf(a0 + bf1(b1[tid]), 0.f);
  h1[tid + 256] = fmaxf(a1 + bf1(b1[tid + 256]), 0.f);
  __syncthreads();
  const u16* w2r = w2 + tid * 512;
  float a = 0.f;
  for (int k = 0; k < 512; k += 8){
    float4 l0 = *(const float4*)(h1 + k);
    float4 l1 = *(const float4*)(h1 + k + 4);
    a = dot8(*(const uint4*)(w2r + k), l0, l1, a);
  }
  float res = x + a + bf1(b2[tid]);
  slots[row * 256 + tid] = res;
  if (lastIter){
    int idx = row * 256 + tid;
    if (f32m) ((float*)out_base)[idx] = res;
    else      ((u16*)out_base)[idx]   = f2bf(res);
  }
}

// ---------- launch ----------
extern "C" void kernel_launch(void* const* d_in, const int* in_sizes, int n_in,
                              void* d_out, int out_size, void* d_ws, size_t ws_size,
                              hipStream_t stream)
{
  char* ws = (char*)d_ws;
  int*  flagp    = (int*)ws;                        // [0,256)
  u16*  cw       = (u16*)(ws + 256);                // 1719808 -> 1720064
  _Float16* qh   = (_Float16*)(ws + 1720064);       //  262144 -> 1982208
  _Float16* wkvh = (_Float16*)(ws + 1982208);       //  262144 -> 2244352
  float* slots   = (float*)(ws + 2244352);          //  524288 -> 2768640
  float* mid     = (float*)(ws + 2768640);          //  524288 -> 3292928
  float* numer   = (float*)(ws + 3292928);          //  524288 -> 3817216
  float* denom   = (float*)(ws + 3817216);          //   16384 -> 3833600
  _Float16* kh   = (_Float16*)(ws + 3833600);       // 67108864 -> 70942464
  _Float16* vT   = (_Float16*)(ws + 70942464);      // 67108864 -> 138051328
  // aliases (dead before the iteration loop):
  float*  beta   = (float*)(ws + 3817216);          // 2 KB in denom region
  float*  colsum = beta + 512;                      // next 2 KB in denom region

  CanonArgs ca;
  ca.p[0]  = d_in[0];   ca.p[1]  = d_in[2];   ca.p[2]  = d_in[3];
  ca.p[3]  = d_in[4];   ca.p[4]  = d_in[5];   ca.p[5]  = d_in[6];
  ca.p[6]  = d_in[7];   ca.p[7]  = d_in[8];   ca.p[8]  = d_in[9];
  ca.p[9]  = d_in[10];  ca.p[10] = d_in[11];  ca.p[11] = d_in[12];
  ca.p[12] = d_in[13];  ca.p[13] = d_in[14];  ca.p[14] = d_in[15];
  ca.p[15] = d_in[16];  ca.p[16] = d_in[17];  ca.p[17] = d_in[18];

  k_flag<<<1, 256, 0, stream>>>((const u16*)d_in[1], flagp);
  k_canon<<<(CW_TOTAL + 255) / 256, 256, 0, stream>>>(ca, flagp, cw);
  k_init<<<1024, 256, 0, stream>>>(cw, slots, wkvh);
  k_beta<<<2, 256, 0, stream>>>(cw, beta, colsum);
  k1_gemm<<<dim3(1024, 2), 256, 0, stream>>>(d_in[1], flagp, beta, colsum, wkvh, kh, vT);
  for (int it = 0; it < 3; it++){
    int last = (it == 2) ? 1 : 0;
    k2_q<<<512, 256, 0, stream>>>(slots, cw, qh);
    k_zero<<<528, 256, 0, stream>>>(numer, 135168);   // numer(131072) + denom(4096) contiguous
    k3_attn<<<dim3(16, 32), 256, 0, stream>>>(kh, vT, qh, denom, numer, d_out, flagp, last);
    k4a_gru<<<dim3(8, 64), 256, 0, stream>>>(slots, numer, denom, cw, mid);
    k4b_mlp<<<512, 256, 0, stream>>>(mid, cw, slots, d_out, flagp, last);
  }
}